// Round 16
// baseline (174.969 us; speedup 1.0000x reference)
//
#include <hip/hip_runtime.h>
#include <hip/hip_bf16.h>

#define B_ 32
#define T_ 256
#define NIN_ 128
#define H_ 32
#define NOUT_ 128
#define R_ (B_ * T_)   // 8192 rows

#define C2L2E 2.88539008177792681472f   // 2*log2(e)
#define L2E   1.44269504088896341f
#define LN2   0.69314718055994531f

__device__ __forceinline__ float rfl(float x) {
    return __uint_as_float(__builtin_amdgcn_readfirstlane(__float_as_uint(x)));
}
__device__ __forceinline__ float rcpf(float x) { return __builtin_amdgcn_rcpf(x); }

// ---------------------------------------------------------------------------
// Kernel 1 (r10 champion): per block = 8 rows x 32 h (256 threads).
//   y = x @ W_in^T + b_in ; Eh = exp2(c*y@W_h^T) ; Eo = exp2(c*y@W_o^T)
// ---------------------------------------------------------------------------
__global__ void __launch_bounds__(256) k_yho(
        const float* __restrict__ x,
        const float* __restrict__ W_in,
        const float* __restrict__ b_in,
        const float* __restrict__ W_h,
        const float* __restrict__ W_o,
        float* __restrict__ y,
        float* __restrict__ Eh,
        float* __restrict__ Eo) {
    __shared__ float xs[8][NIN_];   // 4 KB
    __shared__ float ys[8][H_];     // 1 KB
    const int t   = threadIdx.x;
    const int r   = t >> 5;              // local row 0..7
    const int hh  = t & 31;
    const int row = blockIdx.x * 8 + r;
    const int idx = row * H_ + hh;

    reinterpret_cast<float4*>(&xs[0][0])[t] =
        reinterpret_cast<const float4*>(x + (blockIdx.x * 8) * NIN_)[t];
    __syncthreads();

    {
        const float4* xl = reinterpret_cast<const float4*>(&xs[r][0]);
        const float4* w4 = reinterpret_cast<const float4*>(W_in + hh * NIN_);
        float a0 = b_in[hh], a1 = 0.f;
        #pragma unroll
        for (int k = 0; k < NIN_ / 8; ++k) {
            float4 xv0 = xl[2 * k],     wv0 = w4[2 * k];
            float4 xv1 = xl[2 * k + 1], wv1 = w4[2 * k + 1];
            a0 += xv0.x * wv0.x + xv0.y * wv0.y + xv0.z * wv0.z + xv0.w * wv0.w;
            a1 += xv1.x * wv1.x + xv1.y * wv1.y + xv1.z * wv1.z + xv1.w * wv1.w;
        }
        float acc = a0 + a1;
        ys[r][hh] = acc;
        y[idx] = acc;
    }
    __syncthreads();

    {
        const float4* y4  = reinterpret_cast<const float4*>(&ys[r][0]);
        const float4* wh4 = reinterpret_cast<const float4*>(W_h + hh * H_);
        const float4* wo4 = reinterpret_cast<const float4*>(W_o + hh * H_);
        float ah0 = 0.f, ah1 = 0.f, ao0 = 0.f, ao1 = 0.f;
        #pragma unroll
        for (int k = 0; k < H_ / 8; ++k) {
            float4 yv0 = y4[2 * k],     hv0 = wh4[2 * k],     ov0 = wo4[2 * k];
            float4 yv1 = y4[2 * k + 1], hv1 = wh4[2 * k + 1], ov1 = wo4[2 * k + 1];
            ah0 += yv0.x * hv0.x + yv0.y * hv0.y + yv0.z * hv0.z + yv0.w * hv0.w;
            ah1 += yv1.x * hv1.x + yv1.y * hv1.y + yv1.z * hv1.z + yv1.w * hv1.w;
            ao0 += yv0.x * ov0.x + yv0.y * ov0.y + yv0.z * ov0.z + yv0.w * ov0.w;
            ao1 += yv1.x * ov1.x + yv1.y * ov1.y + yv1.z * ov1.z + yv1.w * ov1.w;
        }
        Eh[idx] = __builtin_amdgcn_exp2f((ah0 + ah1) * C2L2E);
        Eo[idx] = __builtin_amdgcn_exp2f((ao0 + ao1) * C2L2E);
    }
}

// ---------------------------------------------------------------------------
// Kernel 2: EXACT r10 champion body, wrapped in a 2x idempotent loop so the
// dispatch (~2x k_att) rises ABOVE the harness's 40us fill kernels in the
// top-5 profile and we finally get a full PMC row for it. Same inputs ->
// same values both iterations -> deterministic, same final out.
// ---------------------------------------------------------------------------
__global__ void __launch_bounds__(512, 4) k_att(
        const float* __restrict__ y,
        const float* __restrict__ Eh,
        const float* __restrict__ Eo,
        const float* __restrict__ V,
        const float* __restrict__ W_out,
        const float* __restrict__ b_out,
        float* __restrict__ out) {
    __shared__ float eo_swz[T_ * H_];      // 32 KB
    __shared__ float att_t[8][2][T_];      // 16 KB, transposed index
    __shared__ float ctx_lds[8][2][H_];    // 2 KB

    const int t    = threadIdx.x;
    const int w    = __builtin_amdgcn_readfirstlane(t >> 6);  // wave 0..7
    const int lane = t & 63;
    const int r0   = blockIdx.x * 16 + 2 * w;   // query rows r0, r0+1
    const int r1   = r0 + 1;
    const int bb   = blockIdx.x >> 4;           // batch (16 queries/block)

    for (int iter = 0; iter < 2; ++iter) {

    // ---- stage Eo tile (swizzled), all 512 threads ----
    {
        const float4* eg = reinterpret_cast<const float4*>(Eo + bb * T_ * H_);
        float4 tmp[4];
        #pragma unroll
        for (int n = 0; n < 4; ++n) tmp[n] = eg[n * 512 + t];
        #pragma unroll
        for (int n = 0; n < 4; ++n) {
            int c = n * 512 + t;
            int j = c >> 3, p = c & 7;
            *reinterpret_cast<float4*>(&eo_swz[j * H_ + (((p ^ j) & 7) << 2)]) = tmp[n];
        }
    }
    __syncthreads();

    // ---- preamble: eh0 -> SGPR, eh1 -> VGPR, w2/vsum -> SGPR ----
    float eh0[H_];   // rfl'd -> SGPR
    float eh1[H_];   // VGPR
    float w2[H_];    // rfl'd -> SGPR
    float vsum = 0.f;
    {
        const float4* h04 = reinterpret_cast<const float4*>(Eh + r0 * H_);
        const float4* h14 = reinterpret_cast<const float4*>(Eh + r1 * H_);
        const float4* V4  = reinterpret_cast<const float4*>(V);
        #pragma unroll
        for (int p = 0; p < 8; ++p) {
            float4 a = h04[p], b = h14[p], v = V4[p];
            eh0[4 * p + 0] = rfl(a.x); eh0[4 * p + 1] = rfl(a.y);
            eh0[4 * p + 2] = rfl(a.z); eh0[4 * p + 3] = rfl(a.w);
            eh1[4 * p + 0] = b.x; eh1[4 * p + 1] = b.y;
            eh1[4 * p + 2] = b.z; eh1[4 * p + 3] = b.w;
            w2[4 * p + 0] = rfl(v.x * -2.0f); w2[4 * p + 1] = rfl(v.y * -2.0f);
            w2[4 * p + 2] = rfl(v.z * -2.0f); w2[4 * p + 3] = rfl(v.w * -2.0f);
            vsum += v.x + v.y + v.z + v.w;
        }
        vsum = rfl(vsum);
    }

    // ---- e for 4 j's per lane, both queries; Eo rows from LDS ----
    float E0[4], E1[4];
    #pragma unroll
    for (int q = 0; q < 4; ++q) {
        const int j  = lane + 64 * q;
        const int jb = j * H_;
        const int jx = (j & 7) << 2;
        float4 ev[8];
        #pragma unroll
        for (int p = 0; p < 8; ++p)
            ev[p] = *reinterpret_cast<const float4*>(&eo_swz[jb + ((p << 2) ^ jx)]);
        float a00 = 0.f, a01 = 0.f, a02 = 0.f, a03 = 0.f;
        float a10 = 0.f, a11 = 0.f, a12 = 0.f, a13 = 0.f;
        #pragma unroll
        for (int p = 0; p < 8; ++p) {
            const int k = 4 * p;
            float d;
            d = fmaf(eh0[k + 0], ev[p].x, 1.0f);
            a00 = fmaf(w2[k + 0], rcpf(d), a00);
            d = fmaf(eh1[k + 0], ev[p].x, 1.0f);
            a10 = fmaf(w2[k + 0], rcpf(d), a10);
            d = fmaf(eh0[k + 1], ev[p].y, 1.0f);
            a01 = fmaf(w2[k + 1], rcpf(d), a01);
            d = fmaf(eh1[k + 1], ev[p].y, 1.0f);
            a11 = fmaf(w2[k + 1], rcpf(d), a11);
            d = fmaf(eh0[k + 2], ev[p].z, 1.0f);
            a02 = fmaf(w2[k + 2], rcpf(d), a02);
            d = fmaf(eh1[k + 2], ev[p].z, 1.0f);
            a12 = fmaf(w2[k + 2], rcpf(d), a12);
            d = fmaf(eh0[k + 3], ev[p].w, 1.0f);
            a03 = fmaf(w2[k + 3], rcpf(d), a03);
            d = fmaf(eh1[k + 3], ev[p].w, 1.0f);
            a13 = fmaf(w2[k + 3], rcpf(d), a13);
        }
        E0[q] = ((a00 + a01) + (a02 + a03)) + vsum;
        E1[q] = ((a10 + a11) + (a12 + a13)) + vsum;
    }

    // ---- wave-local softmax (no barriers), per query ----
    float m0 = fmaxf(fmaxf(E0[0], E0[1]), fmaxf(E0[2], E0[3]));
    float m1 = fmaxf(fmaxf(E1[0], E1[1]), fmaxf(E1[2], E1[3]));
    #pragma unroll
    for (int off = 1; off < 64; off <<= 1) {
        m0 = fmaxf(m0, __shfl_xor(m0, off));
        m1 = fmaxf(m1, __shfl_xor(m1, off));
    }
    float s0 = 0.f, s1 = 0.f;
    #pragma unroll
    for (int q = 0; q < 4; ++q) {
        s0 += __builtin_amdgcn_exp2f((E0[q] - m0) * L2E);
        s1 += __builtin_amdgcn_exp2f((E1[q] - m1) * L2E);
    }
    #pragma unroll
    for (int off = 1; off < 64; off <<= 1) {
        s0 += __shfl_xor(s0, off);
        s1 += __shfl_xor(s1, off);
    }
    const float lse0 = m0 + __builtin_amdgcn_logf(s0) * LN2;
    const float lse1 = m1 + __builtin_amdgcn_logf(s1) * LN2;

    // transposed store: att_t[.][.][ (j&31)*8 + (j>>5) ]
    #pragma unroll
    for (int q = 0; q < 4; ++q) {
        const int j = lane + 64 * q;
        const int ti = (j & 31) * 8 + (j >> 5);
        att_t[w][0][ti] = E0[q] - lse0;
        att_t[w][1][ti] = E1[q] - lse1;
    }
    // same-wave LDS produce->consume: ordered by lgkmcnt, no barrier needed

    // ---- context: lane = (channel-group hg 0..7) x (jslice js 0..7),
    //      y rows from global via ONE base + immediate offsets ----
    {
        const int hg = lane & 7;
        const int js = lane >> 3;
        const float4* yb = reinterpret_cast<const float4*>(
            y + bb * T_ * H_ + (js * 32) * H_ + hg * 4);
        float4 c0 = {0, 0, 0, 0}, c1 = {0, 0, 0, 0};
        #pragma unroll
        for (int n = 0; n < 32; ++n) {
            float4 yv = yb[n * (H_ / 4)];          // imm offset n*128B
            float a0 = att_t[w][0][n * 8 + js];
            float a1 = att_t[w][1][n * 8 + js];
            c0.x = fmaf(a0, yv.x, c0.x); c0.y = fmaf(a0, yv.y, c0.y);
            c0.z = fmaf(a0, yv.z, c0.z); c0.w = fmaf(a0, yv.w, c0.w);
            c1.x = fmaf(a1, yv.x, c1.x); c1.y = fmaf(a1, yv.y, c1.y);
            c1.z = fmaf(a1, yv.z, c1.z); c1.w = fmaf(a1, yv.w, c1.w);
        }
        // reduce over js axis (lane bits 3,4,5)
        #pragma unroll
        for (int off = 8; off < 64; off <<= 1) {
            c0.x += __shfl_xor(c0.x, off); c0.y += __shfl_xor(c0.y, off);
            c0.z += __shfl_xor(c0.z, off); c0.w += __shfl_xor(c0.w, off);
            c1.x += __shfl_xor(c1.x, off); c1.y += __shfl_xor(c1.y, off);
            c1.z += __shfl_xor(c1.z, off); c1.w += __shfl_xor(c1.w, off);
        }
        if (js == 0) {
            *reinterpret_cast<float4*>(&ctx_lds[w][0][4 * hg]) = c0;
            *reinterpret_cast<float4*>(&ctx_lds[w][1][4 * hg]) = c1;
        }
    }

    // ---- output projection: 2 channels/lane x 2 queries, W_out shared ----
    float4 cv0[8], cv1[8];
    #pragma unroll
    for (int p = 0; p < 8; ++p) {
        cv0[p] = *reinterpret_cast<const float4*>(&ctx_lds[w][0][4 * p]);
        cv1[p] = *reinterpret_cast<const float4*>(&ctx_lds[w][1][4 * p]);
    }
    #pragma unroll
    for (int ho = 0; ho < 2; ++ho) {
        const int oc = lane + 64 * ho;
        const float4* w4 = reinterpret_cast<const float4*>(W_out + oc * H_);
        float b  = b_out[oc];
        float p0 = 0.f, p0b = 0.f, p1 = 0.f, p1b = 0.f;
        #pragma unroll
        for (int p = 0; p < 8; p += 2) {
            float4 wv0 = w4[p], wv1 = w4[p + 1];
            p0  += wv0.x * cv0[p].x + wv0.y * cv0[p].y + wv0.z * cv0[p].z + wv0.w * cv0[p].w;
            p0b += wv1.x * cv0[p+1].x + wv1.y * cv0[p+1].y + wv1.z * cv0[p+1].z + wv1.w * cv0[p+1].w;
            p1  += wv0.x * cv1[p].x + wv0.y * cv1[p].y + wv0.z * cv1[p].z + wv0.w * cv1[p].w;
            p1b += wv1.x * cv1[p+1].x + wv1.y * cv1[p+1].y + wv1.z * cv1[p+1].z + wv1.w * cv1[p+1].w;
        }
        out[r0 * NOUT_ + oc] = b + p0 + p0b;
        out[r1 * NOUT_ + oc] = b + p1 + p1b;
    }

    __syncthreads();   // separate iterations (idempotent re-run)
    }  // iter
}

// ---------------------------------------------------------------------------
extern "C" void kernel_launch(void* const* d_in, const int* in_sizes, int n_in,
                              void* d_out, int out_size, void* d_ws, size_t ws_size,
                              hipStream_t stream) {
    const float* x     = (const float*)d_in[0];
    const float* W_in  = (const float*)d_in[1];
    const float* b_in  = (const float*)d_in[2];
    const float* W_h   = (const float*)d_in[3];
    const float* W_o   = (const float*)d_in[4];
    const float* V     = (const float*)d_in[5];
    const float* W_out = (const float*)d_in[6];
    const float* b_out = (const float*)d_in[7];
    float* out = (float*)d_out;

    // workspace layout: y | Eh | Eo  (each R_*H_ floats = 1 MB)
    float* y  = (float*)d_ws;
    float* Eh = y + R_ * H_;
    float* Eo = Eh + R_ * H_;

    k_yho<<<R_ / 8, 256, 0, stream>>>(x, W_in, b_in, W_h, W_o, y, Eh, Eo);
    k_att<<<R_ / 16, 512, 0, stream>>>(y, Eh, Eo, V, W_out, b_out, out);
}

// Round 17
// 48.082 us; speedup vs baseline: 3.6390x; 3.6390x over previous
//
#include <hip/hip_runtime.h>
#include <hip/hip_bf16.h>

#define B_ 32
#define T_ 256
#define NIN_ 128
#define H_ 32
#define NOUT_ 128
#define R_ (B_ * T_)   // 8192 rows

#define C2L2E 2.88539008177792681472f   // 2*log2(e)
#define L2E   1.44269504088896341f
#define LN2   0.69314718055994531f

__device__ __forceinline__ float rfl(float x) {
    return __uint_as_float(__builtin_amdgcn_readfirstlane(__float_as_uint(x)));
}
__device__ __forceinline__ float rcpf(float x) { return __builtin_amdgcn_rcpf(x); }

// ---------------------------------------------------------------------------
// Kernel 1 (r10 champion, ~5us): per block = 8 rows x 32 h (256 threads).
//   y = x @ W_in^T + b_in ; Eh = exp2(c*y@W_h^T) ; Eo = exp2(c*y@W_o^T)
// ---------------------------------------------------------------------------
__global__ void __launch_bounds__(256) k_yho(
        const float* __restrict__ x,
        const float* __restrict__ W_in,
        const float* __restrict__ b_in,
        const float* __restrict__ W_h,
        const float* __restrict__ W_o,
        float* __restrict__ y,
        float* __restrict__ Eh,
        float* __restrict__ Eo) {
    __shared__ float xs[8][NIN_];   // 4 KB
    __shared__ float ys[8][H_];     // 1 KB
    const int t   = threadIdx.x;
    const int r   = t >> 5;              // local row 0..7
    const int hh  = t & 31;
    const int row = blockIdx.x * 8 + r;
    const int idx = row * H_ + hh;

    reinterpret_cast<float4*>(&xs[0][0])[t] =
        reinterpret_cast<const float4*>(x + (blockIdx.x * 8) * NIN_)[t];
    __syncthreads();

    {
        const float4* xl = reinterpret_cast<const float4*>(&xs[r][0]);
        const float4* w4 = reinterpret_cast<const float4*>(W_in + hh * NIN_);
        float a0 = b_in[hh], a1 = 0.f;
        #pragma unroll
        for (int k = 0; k < NIN_ / 8; ++k) {
            float4 xv0 = xl[2 * k],     wv0 = w4[2 * k];
            float4 xv1 = xl[2 * k + 1], wv1 = w4[2 * k + 1];
            a0 += xv0.x * wv0.x + xv0.y * wv0.y + xv0.z * wv0.z + xv0.w * wv0.w;
            a1 += xv1.x * wv1.x + xv1.y * wv1.y + xv1.z * wv1.z + xv1.w * wv1.w;
        }
        float acc = a0 + a1;
        ys[r][hh] = acc;
        y[idx] = acc;
    }
    __syncthreads();

    {
        const float4* y4  = reinterpret_cast<const float4*>(&ys[r][0]);
        const float4* wh4 = reinterpret_cast<const float4*>(W_h + hh * H_);
        const float4* wo4 = reinterpret_cast<const float4*>(W_o + hh * H_);
        float ah0 = 0.f, ah1 = 0.f, ao0 = 0.f, ao1 = 0.f;
        #pragma unroll
        for (int k = 0; k < H_ / 8; ++k) {
            float4 yv0 = y4[2 * k],     hv0 = wh4[2 * k],     ov0 = wo4[2 * k];
            float4 yv1 = y4[2 * k + 1], hv1 = wh4[2 * k + 1], ov1 = wo4[2 * k + 1];
            ah0 += yv0.x * hv0.x + yv0.y * hv0.y + yv0.z * hv0.z + yv0.w * hv0.w;
            ah1 += yv1.x * hv1.x + yv1.y * hv1.y + yv1.z * hv1.z + yv1.w * hv1.w;
            ao0 += yv0.x * ov0.x + yv0.y * ov0.y + yv0.z * ov0.z + yv0.w * ov0.w;
            ao1 += yv1.x * ov1.x + yv1.y * ov1.y + yv1.z * ov1.z + yv1.w * ov1.w;
        }
        Eh[idx] = __builtin_amdgcn_exp2f((ah0 + ah1) * C2L2E);
        Eo[idx] = __builtin_amdgcn_exp2f((ao0 + ao1) * C2L2E);
    }
}

// ---------------------------------------------------------------------------
// Kernel 2 (r10 structure, SPILL-FREE rebuild):
//  - plain __launch_bounds__(512): r16 proved (512,4) makes the allocator
//    cap VGPR=64 and spill ~114MB/call of eh/ev arrays to scratch (FETCH
//    228MB, WRITE 219MB measured). Plain bound sizes regs to need.
//  - e-phase in TWO K-HALVES: live set per half ~60 VGPR / ~50 SGPR, fits
//    even a VGPR-64 occupancy target -> no spill possible.
//  - att in PLAIN layout (conflict-free store, broadcast read).
//  - epilogue re-streams ctx quads from LDS (live ~16 regs, not 80).
// ---------------------------------------------------------------------------
__global__ void __launch_bounds__(512) k_att(
        const float* __restrict__ y,
        const float* __restrict__ Eh,
        const float* __restrict__ Eo,
        const float* __restrict__ V,
        const float* __restrict__ W_out,
        const float* __restrict__ b_out,
        float* __restrict__ out) {
    __shared__ float eo_swz[T_ * H_];      // 32 KB
    __shared__ float att_p[8][2][T_];      // 16 KB, plain layout
    __shared__ float ctx_lds[8][2][H_];    // 2 KB

    const int t    = threadIdx.x;
    const int w    = __builtin_amdgcn_readfirstlane(t >> 6);  // wave 0..7
    const int lane = t & 63;
    const int r0   = blockIdx.x * 16 + 2 * w;   // query rows r0, r0+1
    const int r1   = r0 + 1;
    const int bb   = blockIdx.x >> 4;           // batch (16 queries/block)

    // ---- stage Eo tile (swizzled), all 512 threads ----
    {
        const float4* eg = reinterpret_cast<const float4*>(Eo + bb * T_ * H_);
        float4 tmp[4];
        #pragma unroll
        for (int n = 0; n < 4; ++n) tmp[n] = eg[n * 512 + t];
        #pragma unroll
        for (int n = 0; n < 4; ++n) {
            int c = n * 512 + t;
            int j = c >> 3, p = c & 7;
            *reinterpret_cast<float4*>(&eo_swz[j * H_ + (((p ^ j) & 7) << 2)]) = tmp[n];
        }
    }
    __syncthreads();

    // ---- e-phase: two k-halves; only 48 scalars of Eh/V live at a time ----
    const float4* h04 = reinterpret_cast<const float4*>(Eh + r0 * H_);
    const float4* h14 = reinterpret_cast<const float4*>(Eh + r1 * H_);
    const float4* V4  = reinterpret_cast<const float4*>(V);
    float E0[4] = {0.f, 0.f, 0.f, 0.f};
    float E1[4] = {0.f, 0.f, 0.f, 0.f};
    float vsum = 0.f;
    #pragma unroll
    for (int hf = 0; hf < 2; ++hf) {
        float eh0h[16];   // rfl'd -> SGPR
        float eh1h[16];   // VGPR (wave-uniform value)
        float w2h[16];    // rfl'd -> SGPR
        #pragma unroll
        for (int p = 0; p < 4; ++p) {
            float4 a = h04[hf * 4 + p], b = h14[hf * 4 + p], v = V4[hf * 4 + p];
            eh0h[4 * p + 0] = rfl(a.x); eh0h[4 * p + 1] = rfl(a.y);
            eh0h[4 * p + 2] = rfl(a.z); eh0h[4 * p + 3] = rfl(a.w);
            eh1h[4 * p + 0] = b.x; eh1h[4 * p + 1] = b.y;
            eh1h[4 * p + 2] = b.z; eh1h[4 * p + 3] = b.w;
            w2h[4 * p + 0] = rfl(v.x * -2.0f); w2h[4 * p + 1] = rfl(v.y * -2.0f);
            w2h[4 * p + 2] = rfl(v.z * -2.0f); w2h[4 * p + 3] = rfl(v.w * -2.0f);
            vsum += (v.x + v.y) + (v.z + v.w);
        }
        #pragma unroll
        for (int q = 0; q < 4; ++q) {
            const int j  = lane + 64 * q;
            const int jb = j * H_;
            const int jx = (j & 7) << 2;
            float4 ev[4];
            #pragma unroll
            for (int p = 0; p < 4; ++p)
                ev[p] = *reinterpret_cast<const float4*>(
                    &eo_swz[jb + ((((hf * 4 + p)) << 2) ^ jx)]);
            float a00 = 0.f, a01 = 0.f, a10 = 0.f, a11 = 0.f;
            #pragma unroll
            for (int p = 0; p < 4; ++p) {
                const int k = 4 * p;
                a00 = fmaf(w2h[k + 0], rcpf(fmaf(eh0h[k + 0], ev[p].x, 1.f)), a00);
                a10 = fmaf(w2h[k + 0], rcpf(fmaf(eh1h[k + 0], ev[p].x, 1.f)), a10);
                a01 = fmaf(w2h[k + 1], rcpf(fmaf(eh0h[k + 1], ev[p].y, 1.f)), a01);
                a11 = fmaf(w2h[k + 1], rcpf(fmaf(eh1h[k + 1], ev[p].y, 1.f)), a11);
                a00 = fmaf(w2h[k + 2], rcpf(fmaf(eh0h[k + 2], ev[p].z, 1.f)), a00);
                a10 = fmaf(w2h[k + 2], rcpf(fmaf(eh1h[k + 2], ev[p].z, 1.f)), a10);
                a01 = fmaf(w2h[k + 3], rcpf(fmaf(eh0h[k + 3], ev[p].w, 1.f)), a01);
                a11 = fmaf(w2h[k + 3], rcpf(fmaf(eh1h[k + 3], ev[p].w, 1.f)), a11);
            }
            E0[q] += a00 + a01;
            E1[q] += a10 + a11;
        }
    }
    vsum = rfl(vsum);
    #pragma unroll
    for (int q = 0; q < 4; ++q) { E0[q] += vsum; E1[q] += vsum; }

    // ---- wave-local softmax (no barriers), per query ----
    float m0 = fmaxf(fmaxf(E0[0], E0[1]), fmaxf(E0[2], E0[3]));
    float m1 = fmaxf(fmaxf(E1[0], E1[1]), fmaxf(E1[2], E1[3]));
    #pragma unroll
    for (int off = 1; off < 64; off <<= 1) {
        m0 = fmaxf(m0, __shfl_xor(m0, off));
        m1 = fmaxf(m1, __shfl_xor(m1, off));
    }
    float s0 = 0.f, s1 = 0.f;
    #pragma unroll
    for (int q = 0; q < 4; ++q) {
        s0 += __builtin_amdgcn_exp2f((E0[q] - m0) * L2E);
        s1 += __builtin_amdgcn_exp2f((E1[q] - m1) * L2E);
    }
    #pragma unroll
    for (int off = 1; off < 64; off <<= 1) {
        s0 += __shfl_xor(s0, off);
        s1 += __shfl_xor(s1, off);
    }
    const float lse0 = m0 + __builtin_amdgcn_logf(s0) * LN2;
    const float lse1 = m1 + __builtin_amdgcn_logf(s1) * LN2;

    // ---- PLAIN att store: consecutive lanes -> consecutive addresses ----
    #pragma unroll
    for (int q = 0; q < 4; ++q) {
        const int j = lane + 64 * q;
        att_p[w][0][j] = E0[q] - lse0;
        att_p[w][1][j] = E1[q] - lse1;
    }
    // same-wave LDS produce->consume: ordered by lgkmcnt, no barrier needed

    // ---- ctx: lane=(hq 0..7, js 0..7), j=n*8+js, y coalesced from global ----
    {
        const int hq = lane & 7;
        const int js = lane >> 3;
        const float4* yb = reinterpret_cast<const float4*>(
            y + (bb * T_ + js) * H_ + hq * 4);
        float4 c0 = {0, 0, 0, 0}, c1 = {0, 0, 0, 0};
        #pragma unroll
        for (int n = 0; n < 32; ++n) {
            const int jj = n * 8 + js;
            float4 yv = yb[n * 8 * (H_ / 4)];      // wave covers 1KB contiguous
            float a0 = att_p[w][0][jj];            // 8-addr, 8-lane broadcast
            float a1 = att_p[w][1][jj];
            c0.x = fmaf(a0, yv.x, c0.x); c0.y = fmaf(a0, yv.y, c0.y);
            c0.z = fmaf(a0, yv.z, c0.z); c0.w = fmaf(a0, yv.w, c0.w);
            c1.x = fmaf(a1, yv.x, c1.x); c1.y = fmaf(a1, yv.y, c1.y);
            c1.z = fmaf(a1, yv.z, c1.z); c1.w = fmaf(a1, yv.w, c1.w);
        }
        #pragma unroll
        for (int off = 8; off < 64; off <<= 1) {
            c0.x += __shfl_xor(c0.x, off); c0.y += __shfl_xor(c0.y, off);
            c0.z += __shfl_xor(c0.z, off); c0.w += __shfl_xor(c0.w, off);
            c1.x += __shfl_xor(c1.x, off); c1.y += __shfl_xor(c1.y, off);
            c1.z += __shfl_xor(c1.z, off); c1.w += __shfl_xor(c1.w, off);
        }
        if (js == 0) {
            *reinterpret_cast<float4*>(&ctx_lds[w][0][4 * hq]) = c0;
            *reinterpret_cast<float4*>(&ctx_lds[w][1][4 * hq]) = c1;
        }
    }

    // ---- output projection: low register pressure (stream quads) ----
    #pragma unroll
    for (int ho = 0; ho < 2; ++ho) {
        const int oc = lane + 64 * ho;
        const float4* w4 = reinterpret_cast<const float4*>(W_out + oc * H_);
        float b  = b_out[oc];
        float p00 = 0.f, p01 = 0.f, p10 = 0.f, p11 = 0.f;
        #pragma unroll
        for (int p = 0; p < 8; p += 2) {
            float4 wv0 = w4[p], wv1 = w4[p + 1];
            float4 ca0 = *reinterpret_cast<const float4*>(&ctx_lds[w][0][4 * p]);
            float4 ca1 = *reinterpret_cast<const float4*>(&ctx_lds[w][0][4 * p + 4]);
            float4 cb0 = *reinterpret_cast<const float4*>(&ctx_lds[w][1][4 * p]);
            float4 cb1 = *reinterpret_cast<const float4*>(&ctx_lds[w][1][4 * p + 4]);
            p00 += wv0.x * ca0.x + wv0.y * ca0.y + wv0.z * ca0.z + wv0.w * ca0.w;
            p01 += wv1.x * ca1.x + wv1.y * ca1.y + wv1.z * ca1.z + wv1.w * ca1.w;
            p10 += wv0.x * cb0.x + wv0.y * cb0.y + wv0.z * cb0.z + wv0.w * cb0.w;
            p11 += wv1.x * cb1.x + wv1.y * cb1.y + wv1.z * cb1.z + wv1.w * cb1.w;
        }
        out[r0 * NOUT_ + oc] = b + p00 + p01;
        out[r1 * NOUT_ + oc] = b + p10 + p11;
    }
}

// ---------------------------------------------------------------------------
extern "C" void kernel_launch(void* const* d_in, const int* in_sizes, int n_in,
                              void* d_out, int out_size, void* d_ws, size_t ws_size,
                              hipStream_t stream) {
    const float* x     = (const float*)d_in[0];
    const float* W_in  = (const float*)d_in[1];
    const float* b_in  = (const float*)d_in[2];
    const float* W_h   = (const float*)d_in[3];
    const float* W_o   = (const float*)d_in[4];
    const float* V     = (const float*)d_in[5];
    const float* W_out = (const float*)d_in[6];
    const float* b_out = (const float*)d_in[7];
    float* out = (float*)d_out;

    // workspace layout: y | Eh | Eo  (each R_*H_ floats = 1 MB)
    float* y  = (float*)d_ws;
    float* Eh = y + R_ * H_;
    float* Eo = Eh + R_ * H_;

    k_yho<<<R_ / 8, 256, 0, stream>>>(x, W_in, b_in, W_h, W_o, y, Eh, Eo);
    k_att<<<R_ / 16, 512, 0, stream>>>(y, Eh, Eo, V, W_out, b_out, out);
}